// Round 2
// baseline (13906.699 us; speedup 1.0000x reference)
//
#include <hip/hip_runtime.h>
#include <hip/hip_cooperative_groups.h>

namespace cg = cooperative_groups;

// B=32, T=128, P=4, D_IN=512, H=512, C=4096, 4C=16384
#define NB 32
#define NT 128
#define NP 4
#define ND 512
#define NH 512
#define NC 4096
#define NG 16384

typedef __bf16 bf16x8 __attribute__((ext_vector_type(8)));
typedef float f32x4 __attribute__((ext_vector_type(4)));

__device__ inline unsigned short f2bf_u(float f) {
  unsigned int u = __float_as_uint(f);
  unsigned int r = u + 0x7FFFu + ((u >> 16) & 1u);  // RNE truncate to bf16
  return (unsigned short)(r >> 16);
}
__device__ inline float bf2f(unsigned short s) {
  return __uint_as_float(((unsigned int)s) << 16);
}
__device__ inline float sigm(float x) { return 1.f / (1.f + __expf(-x)); }
__device__ inline float tanh_(float x) { return 1.f - 2.f / (__expf(2.f * x) + 1.f); }

// ---------------------------------------------------------------------------
// prep: cast weights / x to bf16, zero prev_st buffer
// ---------------------------------------------------------------------------
__global__ __launch_bounds__(256) void prep_kernel(
    const float* __restrict__ x, const float* __restrict__ W_in,
    const float* __restrict__ W_state, const float* __restrict__ W_proj,
    unsigned short* __restrict__ xA, unsigned short* __restrict__ Win_b,
    unsigned short* __restrict__ Wst_b, unsigned short* __restrict__ Wp_b,
    unsigned short* __restrict__ pstb) {
  long i = (long)blockIdx.x * 256 + threadIdx.x;
  long stride = (long)gridDim.x * 256;
  for (long k = i; k < (long)NG * ND; k += stride) {  // 8388608
    Win_b[k] = f2bf_u(W_in[k]);
    Wst_b[k] = f2bf_u(W_state[k]);
    if (k < (long)NH * NC) Wp_b[k] = f2bf_u(W_proj[k]);
    if (k < (long)NB * NT * ND) {
      if (k < (long)NH * NC) xA[k] = f2bf_u(x[k]);  // NB*NT*ND == NH*NC == 2M
    }
    if (k < NB * NH) pstb[k] = 0;
  }
}

// ---------------------------------------------------------------------------
// proj GEMM: proj[m][n] = sum_k xA[m][k] * Win[n][k]; M=4096, N=16384, K=512
// 128x128 tile, BK=32, 4 waves each 64x64. Output bf16.
// ---------------------------------------------------------------------------
__global__ __launch_bounds__(256) void gemm_proj(
    const unsigned short* __restrict__ A, const unsigned short* __restrict__ Bw,
    unsigned short* __restrict__ Cb) {
  __shared__ unsigned short As[128][40];  // 80B rows: 16B-aligned, ~2-way banks
  __shared__ unsigned short Bs[128][40];
  const int tid = threadIdx.x;
  const int lane = tid & 63, wv = tid >> 6;
  const int m0 = blockIdx.y * 128, n0 = blockIdx.x * 128;
  const int wr = (wv >> 1) * 64, wc = (wv & 1) * 64;
  f32x4 acc[4][4] = {};
  const int ar = lane & 15, kg = (lane >> 4) * 8;
  for (int kt = 0; kt < ND; kt += 32) {
#pragma unroll
    for (int i = 0; i < 2; ++i) {
      int chunk = tid + i * 256;
      int row = chunk >> 2, q = chunk & 3;
      *reinterpret_cast<bf16x8*>(&As[row][q * 8]) =
          *reinterpret_cast<const bf16x8*>(&A[(long)(m0 + row) * ND + kt + q * 8]);
      *reinterpret_cast<bf16x8*>(&Bs[row][q * 8]) =
          *reinterpret_cast<const bf16x8*>(&Bw[(long)(n0 + row) * ND + kt + q * 8]);
    }
    __syncthreads();
    bf16x8 bfr[4];
#pragma unroll
    for (int nt = 0; nt < 4; ++nt)
      bfr[nt] = *reinterpret_cast<const bf16x8*>(&Bs[wc + nt * 16 + ar][kg]);
#pragma unroll
    for (int mt = 0; mt < 4; ++mt) {
      bf16x8 af = *reinterpret_cast<const bf16x8*>(&As[wr + mt * 16 + ar][kg]);
#pragma unroll
      for (int nt = 0; nt < 4; ++nt)
        acc[mt][nt] = __builtin_amdgcn_mfma_f32_16x16x32_bf16(af, bfr[nt], acc[mt][nt], 0, 0, 0);
    }
    __syncthreads();
  }
  const int cn = lane & 15, rg = (lane >> 4) * 4;
#pragma unroll
  for (int mt = 0; mt < 4; ++mt)
#pragma unroll
    for (int nt = 0; nt < 4; ++nt)
#pragma unroll
      for (int r = 0; r < 4; ++r) {
        int m = m0 + wr + mt * 16 + rg + r;
        int n = n0 + wc + nt * 16 + cn;
        Cb[(long)m * NG + n] = f2bf_u(acc[mt][nt][r]);
      }
}

// ---------------------------------------------------------------------------
// persistent cooperative scan kernel: 256 blocks x 256 threads
// per step: Phase A (state GEMM + gates + mem, channel-partitioned) | sync |
//           Phase B (output proj partials, K-split 8)               | sync |
//           Phase C (reduce+clip h, write out, pre-gather prev_st)  | sync
// ---------------------------------------------------------------------------
struct ScanArgs {
  const int* prev_idx;          // [B][T][P]
  const float* prev_w;          // [B][T][P]
  const float* b_state;         // [4C]
  const unsigned short* Wst;    // [4C][H] bf16
  const unsigned short* Wp;     // [H][C] bf16
  const unsigned short* proj;   // [B*T][4C] bf16 (row m = b*T + t)
  float* mem_buf;               // [T][B][C]
  float* st_buf;                // [T][B][H]
  unsigned short* u_b;          // [B][C] bf16
  float* partials;              // [8][B][H]
  unsigned short* pstb;         // [B][H] bf16 (pooled prev state for next A)
  float* out;                   // [B][T][H]
};

__global__ __launch_bounds__(256) void scan_kernel(ScanArgs a) {
  cg::grid_group grid = cg::this_grid();
  __shared__ float sA[4][NB][16];  // gate preactivations for this block's 16 ch
  const int tid = threadIdx.x, lane = tid & 63, wv = tid >> 6;
  const int blk = blockIdx.x;
  const int c0 = blk * 16;
  const int ar = lane & 15, kg = (lane >> 4) * 8;
  const int cn = lane & 15, rg = (lane >> 4) * 4;

  for (int t = 0; t < NT; ++t) {
    // ---- Phase A: g = pi + prev_st @ Wst^T + b; gates; mem; u ----
    {
      f32x4 acc[2] = {};
      const unsigned short* wrow = &a.Wst[(long)(wv * NC + c0 + ar) * NH];
#pragma unroll 4
      for (int kk = 0; kk < NH; kk += 32) {
        bf16x8 bfr = *reinterpret_cast<const bf16x8*>(&wrow[kk + kg]);
#pragma unroll
        for (int mt = 0; mt < 2; ++mt) {
          bf16x8 afr = *reinterpret_cast<const bf16x8*>(&a.pstb[(mt * 16 + ar) * NH + kk + kg]);
          acc[mt] = __builtin_amdgcn_mfma_f32_16x16x32_bf16(afr, bfr, acc[mt], 0, 0, 0);
        }
      }
#pragma unroll
      for (int mt = 0; mt < 2; ++mt)
#pragma unroll
        for (int r = 0; r < 4; ++r) {
          int b = mt * 16 + rg + r;
          int g = wv * NC + c0 + cn;
          float pi = bf2f(a.proj[(long)(b * NT + t) * NG + g]);
          sA[wv][b][cn] = acc[mt][r] + pi + a.b_state[g];
        }
      __syncthreads();
#pragma unroll
      for (int rr = 0; rr < 2; ++rr) {
        int item = rr * 256 + tid;
        int b = item >> 4, cl = item & 15, c = c0 + cl;
        float gi = sigm(sA[0][b][cl]);
        float gf = sigm(sA[1][b][cl]);
        float gm = tanh_(sA[2][b][cl]);
        float go = sigm(sA[3][b][cl]);
        const int* ip = &a.prev_idx[(b * NT + t) * NP];
        const float* wp = &a.prev_w[(b * NT + t) * NP];
        float pm = 0.f;
#pragma unroll
        for (int p = 0; p < NP; ++p)
          pm += wp[p] * a.mem_buf[(long)(ip[p] * NB + b) * NC + c];
        float mem = gi * gm + gf * pm;
        mem = fminf(fmaxf(mem, -3.f), 3.f);
        a.mem_buf[(long)(t * NB + b) * NC + c] = mem;
        a.u_b[b * NC + c] = f2bf_u(go * tanh_(mem));
      }
      __syncthreads();
    }
    grid.sync();
    // ---- Phase B: partials[ks] = u[:,ks-slice] @ Wp[:,ks-slice]^T ----
    {
      const int ks = blk >> 5, dg = blk & 31, d0 = dg * 16;
      if (wv < 2) {
        const int mt = wv;
        f32x4 acc = {};
#pragma unroll 4
        for (int kk = 0; kk < 512; kk += 32) {
          int k = ks * 512 + kk + kg;
          bf16x8 afr = *reinterpret_cast<const bf16x8*>(&a.u_b[(mt * 16 + ar) * NC + k]);
          bf16x8 bfr = *reinterpret_cast<const bf16x8*>(&a.Wp[(long)(d0 + ar) * NC + k]);
          acc = __builtin_amdgcn_mfma_f32_16x16x32_bf16(afr, bfr, acc, 0, 0, 0);
        }
#pragma unroll
        for (int r = 0; r < 4; ++r) {
          int b = mt * 16 + rg + r;
          a.partials[(long)(ks * NB + b) * NH + d0 + cn] = acc[r];
        }
      }
    }
    grid.sync();
    // ---- Phase C: reduce partials, clip, write h/out, pre-gather prev_st ----
    if (blk < 64) {
      int dl = tid & 7, b = tid >> 3;
      int dim = blk * 8 + dl;
      float s = 0.f;
#pragma unroll
      for (int ks = 0; ks < 8; ++ks) s += a.partials[(long)(ks * NB + b) * NH + dim];
      float h = fminf(fmaxf(s, -3.f), 3.f);
      a.st_buf[(long)(t * NB + b) * NH + dim] = h;
      a.out[(long)(b * NT + t) * NH + dim] = h;
      if (t + 1 < NT) {
        const int* ip = &a.prev_idx[(b * NT + t + 1) * NP];
        const float* wp = &a.prev_w[(b * NT + t + 1) * NP];
        float ps = 0.f;
#pragma unroll
        for (int p = 0; p < NP; ++p)
          ps += wp[p] * a.st_buf[(long)(ip[p] * NB + b) * NH + dim];
        a.pstb[b * NH + dim] = f2bf_u(ps);
      }
    }
    grid.sync();
  }
}

// ---------------------------------------------------------------------------
extern "C" void kernel_launch(void* const* d_in, const int* in_sizes, int n_in,
                              void* d_out, int out_size, void* d_ws, size_t ws_size,
                              hipStream_t stream) {
  const float* x = (const float*)d_in[0];
  const int* prev_idx = (const int*)d_in[1];
  const float* prev_w = (const float*)d_in[2];
  const float* W_in = (const float*)d_in[3];
  const float* W_state = (const float*)d_in[4];
  const float* b_state = (const float*)d_in[5];
  const float* W_proj = (const float*)d_in[6];

  char* ws = (char*)d_ws;
  size_t off = 0;
  auto alloc = [&](size_t bytes) {
    void* p = ws + off;
    off += (bytes + 255) & ~(size_t)255;
    return p;
  };
  unsigned short* Wst_b = (unsigned short*)alloc((size_t)NG * NH * 2);
  unsigned short* Win_b = (unsigned short*)alloc((size_t)NG * ND * 2);
  unsigned short* Wp_b = (unsigned short*)alloc((size_t)NH * NC * 2);
  unsigned short* xA_b = (unsigned short*)alloc((size_t)NB * NT * ND * 2);
  unsigned short* proj_b = (unsigned short*)alloc((size_t)NB * NT * NG * 2);  // 134MB
  float* mem_buf = (float*)alloc((size_t)NT * NB * NC * 4);                   // 67MB
  float* st_buf = (float*)alloc((size_t)NT * NB * NH * 4);
  unsigned short* u_b = (unsigned short*)alloc((size_t)NB * NC * 2);
  float* partials = (float*)alloc((size_t)8 * NB * NH * 4);
  unsigned short* pstb = (unsigned short*)alloc((size_t)NB * NH * 2);

  prep_kernel<<<4096, 256, 0, stream>>>(x, W_in, W_state, W_proj, xA_b, Win_b,
                                        Wst_b, Wp_b, pstb);
  dim3 g(NG / 128, (NB * NT) / 128);
  gemm_proj<<<g, 256, 0, stream>>>(xA_b, Win_b, proj_b);

  ScanArgs sa;
  sa.prev_idx = prev_idx;
  sa.prev_w = prev_w;
  sa.b_state = b_state;
  sa.Wst = Wst_b;
  sa.Wp = Wp_b;
  sa.proj = proj_b;
  sa.mem_buf = mem_buf;
  sa.st_buf = st_buf;
  sa.u_b = u_b;
  sa.partials = partials;
  sa.pstb = pstb;
  sa.out = (float*)d_out;
  void* params[] = {&sa};
  hipLaunchCooperativeKernel((const void*)scan_kernel, dim3(256), dim3(256),
                             params, 0, stream);
}

// Round 3
// 7518.977 us; speedup vs baseline: 1.8495x; 1.8495x over previous
//
#include <hip/hip_runtime.h>

// B=32, T=128, P=4, D_IN=512, H=512, C=4096, 4C=16384
#define NB 32
#define NT 128
#define NP 4
#define ND 512
#define NH 512
#define NC 4096
#define NG 16384
#define NBLK 256

// LDS layout (dynamic, 122880 B total)
#define WST_OFF 0        // 64 rows (4 gates x 16 ch) x 1024B, swizzled
#define PST_OFF 65536    // 32 rows (batch) x 1024B, swizzled
#define WP_OFF  98304    // 16 rows (dims) x 1024B, swizzled
#define SA_OFF  114688   // float[4][32][16]
#define SMEM_BYTES 122880

typedef __bf16 bf16x8 __attribute__((ext_vector_type(8)));
typedef float f32x4 __attribute__((ext_vector_type(4)));

__device__ inline unsigned short f2bf_u(float f) {
  unsigned int u = __float_as_uint(f);
  unsigned int r = u + 0x7FFFu + ((u >> 16) & 1u);  // RNE
  return (unsigned short)(r >> 16);
}
__device__ inline float bf2f(unsigned short s) {
  return __uint_as_float(((unsigned int)s) << 16);
}
__device__ inline float sigm(float x) { return 1.f / (1.f + __expf(-x)); }
__device__ inline float tanh_(float x) { return 1.f - 2.f / (__expf(2.f * x) + 1.f); }

// ---------------------------------------------------------------------------
// prep: cast weights / x to bf16, zero pstb + barrier counters
// ---------------------------------------------------------------------------
__global__ __launch_bounds__(256) void prep_kernel(
    const float* __restrict__ x, const float* __restrict__ W_in,
    const float* __restrict__ W_state, const float* __restrict__ W_proj,
    unsigned short* __restrict__ xA, unsigned short* __restrict__ Win_b,
    unsigned short* __restrict__ Wst_b, unsigned short* __restrict__ Wp_b,
    unsigned short* __restrict__ pstb, unsigned int* __restrict__ bars) {
  long i = (long)blockIdx.x * 256 + threadIdx.x;
  long stride = (long)gridDim.x * 256;
  for (long k = i; k < (long)NG * ND; k += stride) {  // 8388608
    Win_b[k] = f2bf_u(W_in[k]);
    Wst_b[k] = f2bf_u(W_state[k]);
    if (k < (long)NH * NC) Wp_b[k] = f2bf_u(W_proj[k]);
    if (k < (long)NB * NT * ND) {
      if (k < (long)NH * NC) xA[k] = f2bf_u(x[k]);  // both == 2M
    }
    if (k < NB * NH) pstb[k] = 0;
    if (k < 1024) bars[k] = 0;
  }
}

// ---------------------------------------------------------------------------
// proj GEMM: proj[m][n] = sum_k xA[m][k] * Win[n][k]; M=4096, N=16384, K=512
// ---------------------------------------------------------------------------
__global__ __launch_bounds__(256) void gemm_proj(
    const unsigned short* __restrict__ A, const unsigned short* __restrict__ Bw,
    unsigned short* __restrict__ Cb) {
  __shared__ unsigned short As[128][40];
  __shared__ unsigned short Bs[128][40];
  const int tid = threadIdx.x;
  const int lane = tid & 63, wv = tid >> 6;
  const int m0 = blockIdx.y * 128, n0 = blockIdx.x * 128;
  const int wr = (wv >> 1) * 64, wc = (wv & 1) * 64;
  f32x4 acc[4][4] = {};
  const int ar = lane & 15, kg = (lane >> 4) * 8;
  for (int kt = 0; kt < ND; kt += 32) {
#pragma unroll
    for (int i = 0; i < 2; ++i) {
      int chunk = tid + i * 256;
      int row = chunk >> 2, q = chunk & 3;
      *reinterpret_cast<bf16x8*>(&As[row][q * 8]) =
          *reinterpret_cast<const bf16x8*>(&A[(long)(m0 + row) * ND + kt + q * 8]);
      *reinterpret_cast<bf16x8*>(&Bs[row][q * 8]) =
          *reinterpret_cast<const bf16x8*>(&Bw[(long)(n0 + row) * ND + kt + q * 8]);
    }
    __syncthreads();
    bf16x8 bfr[4];
#pragma unroll
    for (int nt = 0; nt < 4; ++nt)
      bfr[nt] = *reinterpret_cast<const bf16x8*>(&Bs[wc + nt * 16 + ar][kg]);
#pragma unroll
    for (int mt = 0; mt < 4; ++mt) {
      bf16x8 af = *reinterpret_cast<const bf16x8*>(&As[wr + mt * 16 + ar][kg]);
#pragma unroll
      for (int nt = 0; nt < 4; ++nt)
        acc[mt][nt] = __builtin_amdgcn_mfma_f32_16x16x32_bf16(af, bfr[nt], acc[mt][nt], 0, 0, 0);
    }
    __syncthreads();
  }
  const int cn = lane & 15, rg = (lane >> 4) * 4;
#pragma unroll
  for (int mt = 0; mt < 4; ++mt)
#pragma unroll
    for (int nt = 0; nt < 4; ++nt)
#pragma unroll
      for (int r = 0; r < 4; ++r) {
        int m = m0 + wr + mt * 16 + rg + r;
        int n = n0 + wc + nt * 16 + cn;
        Cb[(long)m * NG + n] = f2bf_u(acc[mt][nt][r]);
      }
}

// ---------------------------------------------------------------------------
// custom grid barrier: one fresh counter per (t, phase)
// ---------------------------------------------------------------------------
__device__ inline void gridbar(unsigned int* ctr) {
  __syncthreads();  // all block stores issued & waited (vmcnt0) before release
  if (threadIdx.x == 0) {
    __hip_atomic_fetch_add(ctr, 1u, __ATOMIC_RELEASE, __HIP_MEMORY_SCOPE_AGENT);
    while (__hip_atomic_load(ctr, __ATOMIC_RELAXED, __HIP_MEMORY_SCOPE_AGENT) < NBLK)
      __builtin_amdgcn_s_sleep(1);
    __threadfence();  // acquire: invalidate L1/L2 so we see remote writes
  }
  __syncthreads();
}

// ---------------------------------------------------------------------------
// persistent cooperative scan kernel: 256 blocks x 256 threads
// ---------------------------------------------------------------------------
struct ScanArgs {
  const int* prev_idx;          // [B][T][P]
  const float* prev_w;          // [B][T][P]
  const float* b_state;         // [4C]
  const unsigned short* Wst;    // [4C][H] bf16
  const unsigned short* Wp;     // [H][C] bf16
  const unsigned short* proj;   // [B*T][4C] bf16
  float* mem_buf;               // [T][B][C]
  float* st_buf;                // [T][B][H]
  unsigned short* u_b;          // [B][C] bf16
  float* partials;              // [8][B][H]
  unsigned short* pstb;         // [B][H] bf16
  float* out;                   // [B][T][H]
  unsigned int* bars;           // [T*3]
};

__global__ __launch_bounds__(256) void scan_kernel(ScanArgs a) {
  extern __shared__ char smem[];
  float* sA = (float*)(smem + SA_OFF);
  const int tid = threadIdx.x, lane = tid & 63, wv = tid >> 6;
  const int blk = blockIdx.x;
  const int c0 = blk * 16;
  const int ar = lane & 15, kg = (lane >> 4) * 8;
  const int cn = lane & 15, rg = (lane >> 4) * 4;
  const int ks = blk >> 5, d0 = (blk & 31) * 16;

  // ---- one-time LDS fill: Wst slice (64 rows x 1024B) + Wp slice (16 rows) --
  for (int c = tid; c < 64 * 64; c += 256) {
    int row = c >> 6, sl = c & 63;
    int gate = row >> 4, ch = row & 15;
    const unsigned short* src = &a.Wst[((long)(gate * NC + c0 + ch)) * NH + sl * 8];
    *(bf16x8*)(smem + WST_OFF + row * 1024 + ((sl * 16) ^ ((row & 7) << 4))) =
        *(const bf16x8*)src;
  }
  for (int c = tid; c < 16 * 64; c += 256) {
    int row = c >> 6, sl = c & 63;
    const unsigned short* src = &a.Wp[((long)(d0 + row)) * NC + ks * 512 + sl * 8];
    *(bf16x8*)(smem + WP_OFF + row * 1024 + ((sl * 16) ^ ((row & 7) << 4))) =
        *(const bf16x8*)src;
  }
  // per-thread constants for phase A epilogue
  const float bst = a.b_state[wv * NC + c0 + cn];
  const int rowB = wv * 16 + ar;       // Wst LDS row for this lane
  const int xrB = (ar & 7) << 4;       // swizzle term (wv*16 keeps row&7 == ar&7)
  __syncthreads();

  for (int t = 0; t < NT; ++t) {
    // ---- Phase A: stage pstb -> LDS; g = pi + pstb @ WstT + b; gates; mem; u
    for (int c = tid; c < 32 * 64; c += 256) {
      int row = c >> 6, sl = c & 63;
      *(bf16x8*)(smem + PST_OFF + row * 1024 + ((sl * 16) ^ ((row & 7) << 4))) =
          *(const bf16x8*)&a.pstb[row * NH + sl * 8];
    }
    __syncthreads();
    {
      f32x4 acc[2] = {};
#pragma unroll
      for (int kk = 0; kk < NH; kk += 32) {
        int off = (kk + kg) * 2;
        bf16x8 bfr = *(const bf16x8*)(smem + WST_OFF + rowB * 1024 + (off ^ xrB));
#pragma unroll
        for (int mt = 0; mt < 2; ++mt) {
          int rowA = mt * 16 + ar;
          bf16x8 afr = *(const bf16x8*)(smem + PST_OFF + rowA * 1024 + (off ^ xrB));
          acc[mt] = __builtin_amdgcn_mfma_f32_16x16x32_bf16(afr, bfr, acc[mt], 0, 0, 0);
        }
      }
      __syncthreads();  // pstb LDS reads done; sA region reuse safe
#pragma unroll
      for (int mt = 0; mt < 2; ++mt)
#pragma unroll
        for (int r = 0; r < 4; ++r) {
          int b = mt * 16 + rg + r;
          float pi = bf2f(a.proj[(long)(b * NT + t) * NG + wv * NC + c0 + cn]);
          sA[(wv * 32 + b) * 16 + cn] = acc[mt][r] + pi + bst;
        }
      __syncthreads();
#pragma unroll
      for (int rr = 0; rr < 2; ++rr) {
        int item = rr * 256 + tid;
        int b = item >> 4, cl = item & 15, c = c0 + cl;
        float gi = sigm(sA[(0 * 32 + b) * 16 + cl]);
        float gf = sigm(sA[(1 * 32 + b) * 16 + cl]);
        float gm = tanh_(sA[(2 * 32 + b) * 16 + cl]);
        float go = sigm(sA[(3 * 32 + b) * 16 + cl]);
        const int* ip = &a.prev_idx[(b * NT + t) * NP];
        const float* wp = &a.prev_w[(b * NT + t) * NP];
        float pm = 0.f;
#pragma unroll
        for (int p = 0; p < NP; ++p)
          pm += wp[p] * a.mem_buf[(long)(ip[p] * NB + b) * NC + c];
        float mem = gi * gm + gf * pm;
        mem = fminf(fmaxf(mem, -3.f), 3.f);
        a.mem_buf[(long)(t * NB + b) * NC + c] = mem;
        a.u_b[b * NC + c] = f2bf_u(go * tanh_(mem));
      }
    }
    gridbar(a.bars + t * 3 + 0);
    // ---- Phase B: partials[ks] = u[:,ks-slice] @ Wp[:,ks-slice]^T (LDS Wp) --
    if (wv < 2) {
      const int mt = wv;
      f32x4 acc = {};
#pragma unroll
      for (int kk = 0; kk < 512; kk += 32) {
        int off = (kk + kg) * 2;
        bf16x8 afr = *(const bf16x8*)&a.u_b[(mt * 16 + ar) * NC + ks * 512 + kk + kg];
        bf16x8 bfr = *(const bf16x8*)(smem + WP_OFF + ar * 1024 + (off ^ xrB));
        acc = __builtin_amdgcn_mfma_f32_16x16x32_bf16(afr, bfr, acc, 0, 0, 0);
      }
#pragma unroll
      for (int r = 0; r < 4; ++r) {
        int b = mt * 16 + rg + r;
        a.partials[(long)(ks * NB + b) * NH + d0 + cn] = acc[r];
      }
    }
    gridbar(a.bars + t * 3 + 1);
    // ---- Phase C: reduce partials, clip, write h/out, pre-gather prev_st ----
    if (blk < 64) {
      int dl = tid & 7, b = tid >> 3;
      int dim = blk * 8 + dl;
      float s = 0.f;
#pragma unroll
      for (int p = 0; p < 8; ++p) s += a.partials[(long)(p * NB + b) * NH + dim];
      float h = fminf(fmaxf(s, -3.f), 3.f);
      a.st_buf[(long)(t * NB + b) * NH + dim] = h;
      a.out[(long)(b * NT + t) * NH + dim] = h;
      if (t + 1 < NT) {
        const int* ip = &a.prev_idx[(b * NT + t + 1) * NP];
        const float* wp = &a.prev_w[(b * NT + t + 1) * NP];
        float ps = 0.f;
#pragma unroll
        for (int p = 0; p < NP; ++p)
          ps += wp[p] * a.st_buf[(long)(ip[p] * NB + b) * NH + dim];
        a.pstb[b * NH + dim] = f2bf_u(ps);
      }
    }
    gridbar(a.bars + t * 3 + 2);
  }
}

// ---------------------------------------------------------------------------
extern "C" void kernel_launch(void* const* d_in, const int* in_sizes, int n_in,
                              void* d_out, int out_size, void* d_ws, size_t ws_size,
                              hipStream_t stream) {
  const float* x = (const float*)d_in[0];
  const int* prev_idx = (const int*)d_in[1];
  const float* prev_w = (const float*)d_in[2];
  const float* W_in = (const float*)d_in[3];
  const float* W_state = (const float*)d_in[4];
  const float* b_state = (const float*)d_in[5];
  const float* W_proj = (const float*)d_in[6];

  char* ws = (char*)d_ws;
  size_t off = 0;
  auto alloc = [&](size_t bytes) {
    void* p = ws + off;
    off += (bytes + 255) & ~(size_t)255;
    return p;
  };
  unsigned short* Wst_b = (unsigned short*)alloc((size_t)NG * NH * 2);
  unsigned short* Win_b = (unsigned short*)alloc((size_t)NG * ND * 2);
  unsigned short* Wp_b = (unsigned short*)alloc((size_t)NH * NC * 2);
  unsigned short* xA_b = (unsigned short*)alloc((size_t)NB * NT * ND * 2);
  unsigned short* proj_b = (unsigned short*)alloc((size_t)NB * NT * NG * 2);
  float* mem_buf = (float*)alloc((size_t)NT * NB * NC * 4);
  float* st_buf = (float*)alloc((size_t)NT * NB * NH * 4);
  unsigned short* u_b = (unsigned short*)alloc((size_t)NB * NC * 2);
  float* partials = (float*)alloc((size_t)8 * NB * NH * 4);
  unsigned short* pstb = (unsigned short*)alloc((size_t)NB * NH * 2);
  unsigned int* bars = (unsigned int*)alloc(4096);

  prep_kernel<<<4096, 256, 0, stream>>>(x, W_in, W_state, W_proj, xA_b, Win_b,
                                        Wst_b, Wp_b, pstb, bars);
  dim3 g(NG / 128, (NB * NT) / 128);
  gemm_proj<<<g, 256, 0, stream>>>(xA_b, Win_b, proj_b);

  static bool attr_set = false;
  if (!attr_set) {
    hipFuncSetAttribute((const void*)scan_kernel,
                        hipFuncAttributeMaxDynamicSharedMemorySize, SMEM_BYTES);
    attr_set = true;
  }

  ScanArgs sa;
  sa.prev_idx = prev_idx;
  sa.prev_w = prev_w;
  sa.b_state = b_state;
  sa.Wst = Wst_b;
  sa.Wp = Wp_b;
  sa.proj = proj_b;
  sa.mem_buf = mem_buf;
  sa.st_buf = st_buf;
  sa.u_b = u_b;
  sa.partials = partials;
  sa.pstb = pstb;
  sa.out = (float*)d_out;
  sa.bars = bars;
  void* params[] = {&sa};
  hipLaunchCooperativeKernel((const void*)scan_kernel, dim3(NBLK), dim3(256),
                             params, SMEM_BYTES, stream);
}

// Round 5
// 2072.716 us; speedup vs baseline: 6.7094x; 3.6276x over previous
//
#include <hip/hip_runtime.h>

// B=32, T=128, P=4, D_IN=512, H=512, C=4096, 4C=16384
#define NB 32
#define NT 128
#define NP 4
#define ND 512
#define NH 512
#define NC 4096
#define NG 16384
#define NBLK 256

// LDS layout (dynamic)
#define WST_OFF 0        // 64 rows x 1024B (4 gates x 16 ch), swizzled
#define WP_OFF 65536     // 16 rows x 1024B (dims), swizzled
#define PST_OFF 81920    // 32 rows x 1024B (pstb fragments / u fragments), swizzled
#define SA_OFF 114688    // float[4][32][16] = 8KB
#define PROJ_OFF 122880  // bf16[32][4][16] = 4KB
#define SMEM_BYTES 126976

typedef __bf16 bf16x8 __attribute__((ext_vector_type(8)));
typedef float f32x4 __attribute__((ext_vector_type(4)));
typedef float f32x2 __attribute__((ext_vector_type(2)));
typedef int i32x4 __attribute__((ext_vector_type(4)));

// per-wave drain of ALL outstanding vmem (incl. inline-asm stores the
// compiler can't see). MUST be executed by every thread before the
// __syncthreads() that precedes a flag post — vmcnt is per-wave state.
#define VDRAIN() asm volatile("s_waitcnt vmcnt(0)" ::: "memory")

__device__ inline unsigned short f2bf_u(float f) {
  unsigned int u = __float_as_uint(f);
  unsigned int r = u + 0x7FFFu + ((u >> 16) & 1u);  // RNE
  return (unsigned short)(r >> 16);
}
__device__ inline float bf2f(unsigned short s) {
  return __uint_as_float(((unsigned int)s) << 16);
}
__device__ inline float sigm(float x) { return 1.f / (1.f + __expf(-x)); }
__device__ inline float tanh_(float x) { return 1.f - 2.f / (__expf(2.f * x) + 1.f); }

// ---- coherent (MALL-level) access helpers: bypass L1+L2 via sc0 sc1 ----
__device__ inline void scstore_u32(void* p, unsigned int v) {
  asm volatile("global_store_dword %0, %1, off sc0 sc1" ::"v"(p), "v"(v) : "memory");
}
__device__ inline void scstore_u16(void* p, unsigned int v) {
  asm volatile("global_store_short %0, %1, off sc0 sc1" ::"v"(p), "v"(v) : "memory");
}
__device__ inline int pollx4(const unsigned int* p, unsigned int tag) {
  i32x4 f;
  asm volatile("global_load_dwordx4 %0, %1, off sc0 sc1\n\ts_waitcnt vmcnt(0)"
               : "=&v"(f) : "v"(p) : "memory");
  return ((unsigned)f.x >= tag) & ((unsigned)f.y >= tag) &
         ((unsigned)f.z >= tag) & ((unsigned)f.w >= tag);
}
__device__ inline int poll1x(const unsigned int* p, unsigned int tag) {
  unsigned int f;
  asm volatile("global_load_dword %0, %1, off sc0 sc1\n\ts_waitcnt vmcnt(0)"
               : "=&v"(f) : "v"(p) : "memory");
  return f >= tag;
}

// stage 32 rows x 512 bf16 from (coherent) global into swizzled LDS rows
__device__ inline void stage_sc_32rows(char* dst, const unsigned short* src,
                                       long stride, int wv, int lane) {
  i32x4 r0, r1, r2, r3, r4, r5, r6, r7;
#define LD1(R, K)                                                              \
  {                                                                            \
    const void* p = src + (long)(wv + (K)*4) * stride + lane * 8;              \
    asm volatile("global_load_dwordx4 %0, %1, off sc0 sc1" : "=&v"(R) : "v"(p)); \
  }
  LD1(r0, 0) LD1(r1, 1) LD1(r2, 2) LD1(r3, 3)
  LD1(r4, 4) LD1(r5, 5) LD1(r6, 6) LD1(r7, 7)
#undef LD1
  asm volatile("s_waitcnt vmcnt(0)" ::: "memory");
  __builtin_amdgcn_sched_barrier(0);
#define ST1(R, K)                                                              \
  {                                                                            \
    int row = wv + (K)*4;                                                      \
    *(i32x4*)(dst + row * 1024 + ((lane * 16) ^ ((row & 7) << 4))) = R;        \
  }
  ST1(r0, 0) ST1(r1, 1) ST1(r2, 2) ST1(r3, 3)
  ST1(r4, 4) ST1(r5, 5) ST1(r6, 6) ST1(r7, 7)
#undef ST1
}

// ---------------------------------------------------------------------------
__global__ __launch_bounds__(256) void prep_kernel(
    const float* __restrict__ x, const float* __restrict__ W_in,
    const float* __restrict__ W_state, const float* __restrict__ W_proj,
    unsigned short* __restrict__ xA, unsigned short* __restrict__ Win_b,
    unsigned short* __restrict__ Wst_b, unsigned short* __restrict__ Wp_b,
    unsigned short* __restrict__ pstb, unsigned int* __restrict__ flags) {
  long i = (long)blockIdx.x * 256 + threadIdx.x;
  long stride = (long)gridDim.x * 256;
  for (long k = i; k < (long)NG * ND; k += stride) {
    Win_b[k] = f2bf_u(W_in[k]);
    Wst_b[k] = f2bf_u(W_state[k]);
    if (k < (long)NH * NC) Wp_b[k] = f2bf_u(W_proj[k]);
    if (k < (long)NB * NT * ND) {
      if (k < (long)NH * NC) xA[k] = f2bf_u(x[k]);
    }
    if (k < NB * NH) pstb[k] = 0;
    if (k < 1024) flags[k] = 0;
  }
}

// ---------------------------------------------------------------------------
__global__ __launch_bounds__(256) void gemm_proj(
    const unsigned short* __restrict__ A, const unsigned short* __restrict__ Bw,
    unsigned short* __restrict__ Cb) {
  __shared__ unsigned short As[128][40];
  __shared__ unsigned short Bs[128][40];
  const int tid = threadIdx.x;
  const int lane = tid & 63, wv = tid >> 6;
  const int m0 = blockIdx.y * 128, n0 = blockIdx.x * 128;
  const int wr = (wv >> 1) * 64, wc = (wv & 1) * 64;
  f32x4 acc[4][4] = {};
  const int ar = lane & 15, kg = (lane >> 4) * 8;
  for (int kt = 0; kt < ND; kt += 32) {
#pragma unroll
    for (int i = 0; i < 2; ++i) {
      int chunk = tid + i * 256;
      int row = chunk >> 2, q = chunk & 3;
      *reinterpret_cast<bf16x8*>(&As[row][q * 8]) =
          *reinterpret_cast<const bf16x8*>(&A[(long)(m0 + row) * ND + kt + q * 8]);
      *reinterpret_cast<bf16x8*>(&Bs[row][q * 8]) =
          *reinterpret_cast<const bf16x8*>(&Bw[(long)(n0 + row) * ND + kt + q * 8]);
    }
    __syncthreads();
    bf16x8 bfr[4];
#pragma unroll
    for (int nt = 0; nt < 4; ++nt)
      bfr[nt] = *reinterpret_cast<const bf16x8*>(&Bs[wc + nt * 16 + ar][kg]);
#pragma unroll
    for (int mt = 0; mt < 4; ++mt) {
      bf16x8 af = *reinterpret_cast<const bf16x8*>(&As[wr + mt * 16 + ar][kg]);
#pragma unroll
      for (int nt = 0; nt < 4; ++nt)
        acc[mt][nt] = __builtin_amdgcn_mfma_f32_16x16x32_bf16(af, bfr[nt], acc[mt][nt], 0, 0, 0);
    }
    __syncthreads();
  }
  const int cn = lane & 15, rg = (lane >> 4) * 4;
#pragma unroll
  for (int mt = 0; mt < 4; ++mt)
#pragma unroll
    for (int nt = 0; nt < 4; ++nt)
#pragma unroll
      for (int r = 0; r < 4; ++r) {
        int m = m0 + wr + mt * 16 + rg + r;
        int n = n0 + wc + nt * 16 + cn;
        Cb[(long)m * NG + n] = f2bf_u(acc[mt][nt][r]);
      }
}

// ---------------------------------------------------------------------------
struct ScanArgs {
  const int* prev_idx;
  const float* prev_w;
  const float* b_state;
  const unsigned short* Wst;
  const unsigned short* Wp;
  const unsigned short* proj;
  float* mem_buf;          // [T][B][C] block-local (normal caching)
  float* st_buf;           // [T][B][H] block-local (normal caching)
  unsigned short* u_b;     // [B][C] coherent
  float* partials;         // [8][B][H] coherent
  unsigned short* pstb;    // [B][H] coherent
  float* out;
  unsigned int* flags1;    // [256] A done
  unsigned int* flags2;    // [256] B done
  unsigned int* flags3;    // [64]  C done
};

__global__ __launch_bounds__(256) void scan_kernel(ScanArgs a) {
  extern __shared__ char smem[];
  float* sAf = (float*)(smem + SA_OFF);
  unsigned short* proj_s = (unsigned short*)(smem + PROJ_OFF);
  const int tid = threadIdx.x, lane = tid & 63, wv = tid >> 6;
  const int blk = blockIdx.x;
  const int c0 = blk * 16;
  const int ar = lane & 15, kg = (lane >> 4) * 8;
  const int cn = lane & 15, rg = (lane >> 4) * 4;
  const int ks = blk >> 5, d0 = (blk & 31) * 16;
  const int xrB = (ar & 7) << 4;

  // one-time LDS fill: Wst (64 rows), Wp (16 rows)
  for (int c = tid; c < 64 * 64; c += 256) {
    int row = c >> 6, sl = c & 63;
    int gate = row >> 4, ch = row & 15;
    *(bf16x8*)(smem + WST_OFF + row * 1024 + ((sl * 16) ^ ((row & 7) << 4))) =
        *(const bf16x8*)&a.Wst[((long)(gate * NC + c0 + ch)) * NH + sl * 8];
  }
  for (int c = tid; c < 16 * 64; c += 256) {
    int row = c >> 6, sl = c & 63;
    *(bf16x8*)(smem + WP_OFF + row * 1024 + ((sl * 16) ^ ((row & 7) << 4))) =
        *(const bf16x8*)&a.Wp[((long)(d0 + row)) * NC + ks * 512 + sl * 8];
  }
  const float bst = a.b_state[wv * NC + c0 + cn];
  const int rowB = wv * 16 + ar;
  // prologue: proj[t=0] -> LDS
  {
    int b = tid >> 3, g = (tid >> 1) & 3, half = tid & 1;
    bf16x8 pv = *(const bf16x8*)&a.proj[(long)(b * NT + 0) * NG + g * NC + c0 + half * 8];
    *(bf16x8*)(smem + PROJ_OFF + ((b * 4 + g) * 16 + half * 8) * 2) = pv;
  }

  for (int t = 0; t < NT; ++t) {
    const unsigned int tag = t + 1;
    // ---- Phase A ----
    stage_sc_32rows(smem + PST_OFF, a.pstb, NH, wv, lane);
    __syncthreads();  // PST + PROJ ready
    {
      f32x4 acc[2] = {};
#pragma unroll
      for (int kk = 0; kk < NH; kk += 32) {
        int off = (kk + kg) * 2;
        bf16x8 bfr = *(const bf16x8*)(smem + WST_OFF + rowB * 1024 + (off ^ xrB));
#pragma unroll
        for (int mt = 0; mt < 2; ++mt) {
          int rowA = mt * 16 + ar;
          bf16x8 afr = *(const bf16x8*)(smem + PST_OFF + rowA * 1024 + (off ^ xrB));
          acc[mt] = __builtin_amdgcn_mfma_f32_16x16x32_bf16(afr, bfr, acc[mt], 0, 0, 0);
        }
      }
#pragma unroll
      for (int mt = 0; mt < 2; ++mt)
#pragma unroll
        for (int r = 0; r < 4; ++r) {
          int b = mt * 16 + rg + r;
          float pi = bf2f(proj_s[(b * 4 + wv) * 16 + cn]);
          sAf[(wv * 32 + b) * 16 + cn] = acc[mt][r] + pi + bst;
        }
      __syncthreads();
      // epilogue: 2 channels per thread
      {
        int b = tid >> 3, cp = tid & 7;
        int cl0 = cp * 2, c = c0 + cl0;
        float i0 = sigm(sAf[(0 * 32 + b) * 16 + cl0]);
        float i1 = sigm(sAf[(0 * 32 + b) * 16 + cl0 + 1]);
        float f0 = sigm(sAf[(1 * 32 + b) * 16 + cl0]);
        float f1 = sigm(sAf[(1 * 32 + b) * 16 + cl0 + 1]);
        float m0 = tanh_(sAf[(2 * 32 + b) * 16 + cl0]);
        float m1 = tanh_(sAf[(2 * 32 + b) * 16 + cl0 + 1]);
        float o0 = sigm(sAf[(3 * 32 + b) * 16 + cl0]);
        float o1 = sigm(sAf[(3 * 32 + b) * 16 + cl0 + 1]);
        const int* ip = &a.prev_idx[(b * NT + t) * NP];
        const float* wpp = &a.prev_w[(b * NT + t) * NP];
        f32x2 pm = {0.f, 0.f};
#pragma unroll
        for (int p = 0; p < NP; ++p) {
          f32x2 m2 = *(const f32x2*)&a.mem_buf[(long)(ip[p] * NB + b) * NC + c];
          pm.x += wpp[p] * m2.x;
          pm.y += wpp[p] * m2.y;
        }
        float me0 = fminf(fmaxf(i0 * m0 + f0 * pm.x, -3.f), 3.f);
        float me1 = fminf(fmaxf(i1 * m1 + f1 * pm.y, -3.f), 3.f);
        f32x2 st2 = {me0, me1};
        *(f32x2*)&a.mem_buf[(long)(t * NB + b) * NC + c] = st2;
        unsigned int pack = (unsigned int)f2bf_u(o0 * tanh_(me0)) |
                            ((unsigned int)f2bf_u(o1 * tanh_(me1)) << 16);
        scstore_u32(&a.u_b[b * NC + c], pack);
      }
      VDRAIN();        // every wave drains its own u/mem stores (asm invisible
      __syncthreads(); // to compiler's pre-barrier waitcnt) before flag post
      if (tid == 0) scstore_u32(&a.flags1[blk], tag);
    }
    // ---- Phase B: wait 32 producer flags, stage u slice, GEMM vs Wp ----
    if (wv == 0) {
      const unsigned int* fp = a.flags1 + ks * 32 + (lane & 7) * 4;
      int act = lane < 8;
      unsigned int cap = 0;
      while (1) {
        int ok = act ? pollx4(fp, tag) : 1;
        if (__all(ok)) break;
        __builtin_amdgcn_s_sleep(2);
        if (++cap > 4000000u) break;
      }
    }
    __syncthreads();
    stage_sc_32rows(smem + PST_OFF, a.u_b + ks * 512, NC, wv, lane);
    __syncthreads();
    if (wv < 2) {
      f32x4 acc = {};
      const int rowA = wv * 16 + ar;
#pragma unroll
      for (int kk = 0; kk < 512; kk += 32) {
        int off = (kk + kg) * 2;
        bf16x8 afr = *(const bf16x8*)(smem + PST_OFF + rowA * 1024 + (off ^ xrB));
        bf16x8 bfr = *(const bf16x8*)(smem + WP_OFF + ar * 1024 + (off ^ xrB));
        acc = __builtin_amdgcn_mfma_f32_16x16x32_bf16(afr, bfr, acc, 0, 0, 0);
      }
#pragma unroll
      for (int r = 0; r < 4; ++r) {
        int b = wv * 16 + rg + r;
        scstore_u32(&a.partials[(long)(ks * NB + b) * NH + d0 + cn],
                    __float_as_uint(acc[r]));
      }
    }
    VDRAIN();        // drain partials stores in EVERY wave before flag post
    __syncthreads();
    if (tid == 0) scstore_u32(&a.flags2[blk], tag);
    // ---- Phase C (blocks 0..63): reduce, clip, out, pstb gather ----
    if (blk < 64) {
      if (wv == 0) {
        int act = lane < 8;
        const unsigned int* fp = a.flags2 + (lane & 7) * 32 + (blk >> 1);
        unsigned int cap = 0;
        while (1) {
          int ok = act ? poll1x(fp, tag) : 1;
          if (__all(ok)) break;
          __builtin_amdgcn_s_sleep(2);
          if (++cap > 4000000u) break;
        }
      }
      __syncthreads();
      {
        int b = tid >> 3, dl = tid & 7, dim = blk * 8 + dl;
        unsigned int q0, q1, q2, q3, q4, q5, q6, q7;
#define LDP(R, KS)                                                         \
  asm volatile("global_load_dword %0, %1, off sc0 sc1"                     \
               : "=&v"(R) : "v"(&a.partials[(long)((KS)*NB + b) * NH + dim]))
        LDP(q0, 0); LDP(q1, 1); LDP(q2, 2); LDP(q3, 3);
        LDP(q4, 4); LDP(q5, 5); LDP(q6, 6); LDP(q7, 7);
#undef LDP
        asm volatile("s_waitcnt vmcnt(0)" ::: "memory");
        __builtin_amdgcn_sched_barrier(0);
        float s = __uint_as_float(q0) + __uint_as_float(q1) +
                  __uint_as_float(q2) + __uint_as_float(q3) +
                  __uint_as_float(q4) + __uint_as_float(q5) +
                  __uint_as_float(q6) + __uint_as_float(q7);
        float h = fminf(fmaxf(s, -3.f), 3.f);
        a.st_buf[(long)(t * NB + b) * NH + dim] = h;
        a.out[((long)b * NT + t) * NH + dim] = h;
        asm volatile("s_waitcnt vmcnt(0)" ::: "memory");  // st_buf visible to own loads
        if (t + 1 < NT) {
          const int* ip = &a.prev_idx[(b * NT + t + 1) * NP];
          const float* wpp = &a.prev_w[(b * NT + t + 1) * NP];
          float ps = 0.f;
#pragma unroll
          for (int p = 0; p < NP; ++p)
            ps += wpp[p] * a.st_buf[(long)(ip[p] * NB + b) * NH + dim];
          scstore_u16(&a.pstb[b * NH + dim], (unsigned int)f2bf_u(ps));
        }
      }
      VDRAIN();        // drain pstb stores in EVERY wave before flag post
      __syncthreads();
      if (tid == 0) scstore_u32(&a.flags3[blk], tag);
    }
    // ---- prefetch proj[t+1] while waiting on flags3 ----
    bf16x8 pv = {};
    int b2 = tid >> 3, g2 = (tid >> 1) & 3, h2 = tid & 1;
    if (t + 1 < NT)
      pv = *(const bf16x8*)&a.proj[(long)(b2 * NT + t + 1) * NG + g2 * NC + c0 + h2 * 8];
    if (wv == 0) {
      int act = lane < 16;
      const unsigned int* fp = a.flags3 + (lane & 15) * 4;
      unsigned int cap = 0;
      while (1) {
        int ok = act ? pollx4(fp, tag) : 1;
        if (__all(ok)) break;
        __builtin_amdgcn_s_sleep(2);
        if (++cap > 4000000u) break;
      }
    }
    __syncthreads();
    if (t + 1 < NT)
      *(bf16x8*)(smem + PROJ_OFF + ((b2 * 4 + g2) * 16 + h2 * 8) * 2) = pv;
  }
}

// ---------------------------------------------------------------------------
extern "C" void kernel_launch(void* const* d_in, const int* in_sizes, int n_in,
                              void* d_out, int out_size, void* d_ws, size_t ws_size,
                              hipStream_t stream) {
  const float* x = (const float*)d_in[0];
  const int* prev_idx = (const int*)d_in[1];
  const float* prev_w = (const float*)d_in[2];
  const float* W_in = (const float*)d_in[3];
  const float* W_state = (const float*)d_in[4];
  const float* b_state = (const float*)d_in[5];
  const float* W_proj = (const float*)d_in[6];

  char* ws = (char*)d_ws;
  size_t off = 0;
  auto alloc = [&](size_t bytes) {
    void* p = ws + off;
    off += (bytes + 255) & ~(size_t)255;
    return p;
  };
  unsigned short* Wst_b = (unsigned short*)alloc((size_t)NG * NH * 2);
  unsigned short* Win_b = (unsigned short*)alloc((size_t)NG * ND * 2);
  unsigned short* Wp_b = (unsigned short*)alloc((size_t)NH * NC * 2);
  unsigned short* xA_b = (unsigned short*)alloc((size_t)NB * NT * ND * 2);
  unsigned short* proj_b = (unsigned short*)alloc((size_t)NB * NT * NG * 2);
  float* mem_buf = (float*)alloc((size_t)NT * NB * NC * 4);
  float* st_buf = (float*)alloc((size_t)NT * NB * NH * 4);
  unsigned short* u_b = (unsigned short*)alloc((size_t)NB * NC * 2);
  float* partials = (float*)alloc((size_t)8 * NB * NH * 4);
  unsigned short* pstb = (unsigned short*)alloc((size_t)NB * NH * 2);
  unsigned int* flags = (unsigned int*)alloc(4096);

  prep_kernel<<<4096, 256, 0, stream>>>(x, W_in, W_state, W_proj, xA_b, Win_b,
                                        Wst_b, Wp_b, pstb, flags);
  dim3 g(NG / 128, (NB * NT) / 128);
  gemm_proj<<<g, 256, 0, stream>>>(xA_b, Win_b, proj_b);

  static bool attr_set = false;
  if (!attr_set) {
    hipFuncSetAttribute((const void*)scan_kernel,
                        hipFuncAttributeMaxDynamicSharedMemorySize, SMEM_BYTES);
    attr_set = true;
  }

  ScanArgs sa;
  sa.prev_idx = prev_idx;
  sa.prev_w = prev_w;
  sa.b_state = b_state;
  sa.Wst = Wst_b;
  sa.Wp = Wp_b;
  sa.proj = proj_b;
  sa.mem_buf = mem_buf;
  sa.st_buf = st_buf;
  sa.u_b = u_b;
  sa.partials = partials;
  sa.pstb = pstb;
  sa.out = (float*)d_out;
  sa.flags1 = flags;
  sa.flags2 = flags + 256;
  sa.flags3 = flags + 512;
  void* params[] = {&sa};
  hipLaunchCooperativeKernel((const void*)scan_kernel, dim3(NBLK), dim3(256),
                             params, SMEM_BYTES, stream);
}